// Round 9
// baseline (49.780 us; speedup 1.0000x reference)
//
#include <hip/hip_runtime.h>
#include <hip/hip_fp16.h>

typedef _Float16 f16;
typedef __attribute__((ext_vector_type(8))) _Float16 f16x8;
typedef __attribute__((ext_vector_type(4))) _Float16 f16x4;
typedef __attribute__((ext_vector_type(4))) float f32x4;
typedef __attribute__((ext_vector_type(2))) float f32x2;

#define MFMA16(a,b,c) __builtin_amdgcn_mfma_f32_16x16x32_f16(a,b,c,0,0,0)
#define EXP2(x) __builtin_amdgcn_exp2f(x)
#define LOG2E 1.4426950408889634f

#define B_DIM 8
#define L_DIM 2048
#define D_DIM 128
#define NGRP 4
#define KVB 32
#define NTILES 16            // 512 kv per group / 32
#define TILE_B 16384         // Vrow 8KB (subtiled/permuted) + V^T 8KB ([d][32kv] rows 64B)
#define TILE_H 8192          // f16 elems per tile in ws
#define P_ST 40              // P row stride f16 (80B rows: 16B-aligned, 2-way free)
#define SLAB_ST 132
#define SMEM_B 137216        // staging 4grp*2buf*16KB=131072; epilogue 135168+2048

__device__ __forceinline__ unsigned ldsa(const void* p) {
    return (unsigned)(unsigned long long)(const __attribute__((address_space(3))) char*)p;
}

#define LGKM0() do { asm volatile("s_waitcnt lgkmcnt(0)" ::: "memory"); __builtin_amdgcn_sched_barrier(0); } while (0)
#define GLDS(gp, lp) __builtin_amdgcn_global_load_lds( \
    (const __attribute__((address_space(1))) unsigned int*)(gp), \
    (__attribute__((address_space(3))) unsigned int*)(lp), 16, 0, 0)

// ---- pre-pass: per 32-kv tile, write Vrow (chunk-permuted for GLDS identity) + V^T ----
__global__ __launch_bounds__(256) void prep_v(const float* __restrict__ V, f16* __restrict__ ws) {
    __shared__ f16 lds[KVB * D_DIM];
    const int blk = blockIdx.x;                    // b*64 + gkv
    const float* src = V + (size_t)blk * (KVB * D_DIM);
    f16* dst = ws + (size_t)blk * TILE_H;
    const int t = threadIdx.x;
    #pragma unroll
    for (int i = 0; i < 4; ++i) {
        int idx4 = (i * 256 + t) * 4;
        f32x4 f = *(const f32x4*)(src + idx4);
        f16x4 h = { (f16)f[0], (f16)f[1], (f16)f[2], (f16)f[3] };
        *(f16x4*)(lds + idx4) = h;
    }
    __syncthreads();
    // Vrow: chunk c <-> (kv,d): off16 = (kv>>2)*64 + (d>>4)*8 + (kv&3)*2 + ((d>>3)&1)
    #pragma unroll
    for (int i = 0; i < 2; ++i) {
        int c = i * 256 + t;
        int kvblk = c >> 6, w = c & 63;
        int d16 = w >> 3, r2 = w & 7;
        int kv = kvblk * 4 + (r2 >> 1), d0 = d16 * 16 + (r2 & 1) * 8;
        f16x8 v = *(const f16x8*)(lds + kv * D_DIM + d0);
        *(f16x8*)(dst + c * 8) = v;
    }
    // V^T: [d][kv] rows of 32 kv (64B); chunk cc -> d=cc>>2, kv8=(cc&3)*8
    #pragma unroll
    for (int i = 0; i < 2; ++i) {
        int cc = i * 256 + t;
        int d = cc >> 2, k8 = (cc & 3) * 8;
        union { f16 h[8]; f16x8 v; } u;
        #pragma unroll
        for (int j = 0; j < 8; ++j) u.h[j] = lds[(k8 + j) * D_DIM + d];
        *(f16x8*)(dst + 4096 + cc * 8) = u.v;
    }
}

__global__ __launch_bounds__(512, 2) void attn_fwd(
    const float* __restrict__ Q, const f16* __restrict__ ws, float* __restrict__ Out)
{
    __shared__ __align__(16) char smem[SMEM_B];

    const int tid  = threadIdx.x;
    const int wv   = tid >> 6;
    const int grp  = wv >> 1;      // kv group 0..3 (512 kv each)
    const int qw   = wv & 1;       // q half (32 rows)
    const int lane = tid & 63;
    const int lrow = lane & 15;
    const int g    = lane >> 4;

    const int blk = blockIdx.x;
    const int b   = blk & 7;
    const int q0  = (blk >> 3) * 64;

    char* grpbase = smem + grp * (2 * TILE_B);

    // ---- Q fragments: fp16 hi/lo split, pre-scaled by log2(e) ----
    f16x8 qhi[2][4], qlo[2][4];
    {
        const float* qb = Q + ((size_t)b * L_DIM + q0 + qw * 32) * D_DIM;
        #pragma unroll
        for (int q2 = 0; q2 < 2; ++q2) {
            const float* qp = qb + (size_t)(q2 * 16 + lrow) * D_DIM + g * 8;
            #pragma unroll
            for (int dt = 0; dt < 4; ++dt) {
                f32x4 f0 = *(const f32x4*)(qp + dt * 32);
                f32x4 f1 = *(const f32x4*)(qp + dt * 32 + 4);
                #pragma unroll
                for (int i = 0; i < 4; ++i) {
                    float s0 = f0[i] * LOG2E;
                    f16 h0 = (f16)s0;
                    qhi[q2][dt][i] = h0;
                    qlo[q2][dt][i] = (f16)(s0 - (float)h0);
                    float s1 = f1[i] * LOG2E;
                    f16 h1 = (f16)s1;
                    qhi[q2][dt][i + 4] = h1;
                    qlo[q2][dt][i + 4] = (f16)(s1 - (float)h1);
                }
            }
        }
    }

    f32x4 acc[2][8];
    #pragma unroll
    for (int q2 = 0; q2 < 2; ++q2)
        #pragma unroll
        for (int i = 0; i < 8; ++i) acc[q2][i] = (f32x4)0.0f;
    float m_run[2] = { -3.0e38f, -3.0e38f }, l_run[2] = { 0.0f, 0.0f };

    // QK A-frag lane offset (bytes within Vrow half)
    const int qkoff = (lrow >> 2) * 1024 + (g >> 1) * 128 + (lrow & 3) * 32 + (g & 1) * 16;

    const f16* wsb = ws + (size_t)b * (64 * TILE_H);   // this batch's ws slice

    // ---- prologue: DMA tile 0 (both halves; wave qw stages half qw) ----
    {
        const f16* w0 = wsb + (size_t)(grp * NTILES) * TILE_H + qw * 4096 + lane * 8;
        char* l0 = grpbase + qw * 8192;
        #pragma unroll
        for (int i = 0; i < 8; ++i) GLDS(w0 + i * 512, l0 + i * 1024);
    }
    __syncthreads();

    for (int t = 0; t < NTILES; ++t) {
        const int c = t & 1;
        char* cur = grpbase + c * TILE_B;
        char* alt = grpbase + (c ^ 1) * TILE_B;

        // ---- QK^T swapped: S^T[kv 32][q 32], fp16 2-pass (log2e-scaled) ----
        f32x4 s[2][2];
        #pragma unroll
        for (int q2 = 0; q2 < 2; ++q2)
            #pragma unroll
            for (int nt = 0; nt < 2; ++nt) s[q2][nt] = (f32x4)0.0f;
        __builtin_amdgcn_s_setprio(1);
        #pragma unroll
        for (int nt = 0; nt < 2; ++nt) {
            #pragma unroll
            for (int dt = 0; dt < 4; ++dt) {
                f16x8 a = *(const f16x8*)(cur + qkoff + nt * 4096 + dt * 256);
                s[0][nt] = MFMA16(a, qhi[0][dt], s[0][nt]);
                s[0][nt] = MFMA16(a, qlo[0][dt], s[0][nt]);
                s[1][nt] = MFMA16(a, qhi[1][dt], s[1][nt]);
                s[1][nt] = MFMA16(a, qlo[1][dt], s[1][nt]);
            }
        }
        __builtin_amdgcn_s_setprio(0);

        // ---- online softmax with defer-max (THR=11.5 in log2 units) ----
        float pm[2];
        #pragma unroll
        for (int q2 = 0; q2 < 2; ++q2) {
            float tm = s[q2][0][0];
            #pragma unroll
            for (int nt = 0; nt < 2; ++nt)
                #pragma unroll
                for (int r = 0; r < 4; ++r) tm = fmaxf(tm, s[q2][nt][r]);
            tm = fmaxf(tm, __shfl_xor(tm, 16));
            tm = fmaxf(tm, __shfl_xor(tm, 32));
            pm[q2] = tm;
        }
        bool need = (pm[0] > m_run[0] + 11.5f) || (pm[1] > m_run[1] + 11.5f);
        if (__any(need)) {
            float scl[2];
            #pragma unroll
            for (int q2 = 0; q2 < 2; ++q2) {
                float mnew = fmaxf(m_run[q2], pm[q2]);
                scl[q2]  = EXP2(m_run[q2] - mnew);
                m_run[q2] = mnew;
                l_run[q2] *= scl[q2];
            }
            float sr[2][4];
            #pragma unroll
            for (int r = 0; r < 4; ++r) {
                sr[0][r] = __shfl(scl[0], g * 4 + r);
                sr[1][r] = __shfl(scl[1], g * 4 + r);
            }
            #pragma unroll
            for (int q2 = 0; q2 < 2; ++q2)
                #pragma unroll
                for (int nd = 0; nd < 8; ++nd)
                    #pragma unroll
                    for (int r = 0; r < 4; ++r) acc[q2][nd][r] *= sr[q2][r];
        }
        #pragma unroll
        for (int q2 = 0; q2 < 2; ++q2) {
            float ps = 0.0f;
            #pragma unroll
            for (int nt = 0; nt < 2; ++nt)
                #pragma unroll
                for (int r = 0; r < 4; ++r) {
                    float p = EXP2(s[q2][nt][r] - m_run[q2]);
                    s[q2][nt][r] = p;
                    ps += p;
                }
            ps += __shfl_xor(ps, 16);
            ps += __shfl_xor(ps, 32);
            l_run[q2] += ps;
        }

        // ---- P -> LDS (dead region: own qw half of alt, pre-DMA), read back as A-frags ----
        f16* pls = (f16*)(alt + qw * 8192);
        #pragma unroll
        for (int q2 = 0; q2 < 2; ++q2) {
            #pragma unroll
            for (int nt = 0; nt < 2; ++nt) {
                f16x4 w = { (f16)s[q2][nt][0], (f16)s[q2][nt][1],
                            (f16)s[q2][nt][2], (f16)s[q2][nt][3] };
                *(f16x4*)(pls + (size_t)(q2 * 16 + lrow) * P_ST + nt * 16 + g * 4) = w;
            }
        }
        f16x8 pa0 = *(const f16x8*)(pls + (size_t)(lrow) * P_ST + g * 8);
        f16x8 pa1 = *(const f16x8*)(pls + (size_t)(16 + lrow) * P_ST + g * 8);
        LGKM0();   // P landed in regs -> safe to DMA-overwrite the slice

        // ---- issue DMA staging of tile t+1 into alt (in flight under PV) ----
        if (t + 1 < NTILES) {
            const f16* wnt = wsb + (size_t)(grp * NTILES + t + 1) * TILE_H + qw * 4096 + lane * 8;
            char* ldst = alt + qw * 8192;
            #pragma unroll
            for (int i = 0; i < 8; ++i) GLDS(wnt + i * 512, ldst + i * 1024);
        }

        // ---- PV: B-frags are plain b128 rows of V^T (conflict-free) ----
        const char* vt = cur + 8192;
        __builtin_amdgcn_s_setprio(1);
        #pragma unroll
        for (int nd = 0; nd < 8; ++nd) {
            f16x8 bf = *(const f16x8*)(vt + (nd * 16 + lrow) * 64 + g * 16);
            acc[0][nd] = MFMA16(pa0, bf, acc[0][nd]);
            acc[1][nd] = MFMA16(pa1, bf, acc[1][nd]);
        }
        __builtin_amdgcn_s_setprio(0);

        __syncthreads();   // drains vmcnt (DMA) + lgkm; next iter reads alt
    }

    // ---- cross-group merge (smem repurposed after final barrier) ----
    float* slab = (float*)smem;                          // [8 waves][32 q][SLAB_ST]
    float* mlp  = (float*)(smem + 8 * 32 * SLAB_ST * 4); // [8 waves][2][32]
    #pragma unroll
    for (int q2 = 0; q2 < 2; ++q2)
        #pragma unroll
        for (int nd = 0; nd < 8; ++nd)
            #pragma unroll
            for (int r = 0; r < 4; ++r)
                slab[(size_t)(wv * 32 + q2 * 16 + g * 4 + r) * SLAB_ST + nd * 16 + lrow] = acc[q2][nd][r];
    if (g == 0) {
        #pragma unroll
        for (int q2 = 0; q2 < 2; ++q2) {
            mlp[wv * 64 + q2 * 16 + lrow]      = m_run[q2];
            mlp[wv * 64 + 32 + q2 * 16 + lrow] = l_run[q2];
        }
    }
    __syncthreads();

    #pragma unroll
    for (int rr = 0; rr < 8; ++rr) {
        int row = wv * 8 + rr;
        int qws = row >> 5, ql = row & 31;
        float mg[4], M = -3.0e38f;
        #pragma unroll
        for (int gg = 0; gg < 4; ++gg) {
            mg[gg] = mlp[(gg * 2 + qws) * 64 + ql];
            M = fmaxf(M, mg[gg]);
        }
        float L = 0.0f, f[4];
        #pragma unroll
        for (int gg = 0; gg < 4; ++gg) {
            f[gg] = EXP2(mg[gg] - M);
            L += f[gg] * mlp[(gg * 2 + qws) * 64 + 32 + ql];
        }
        float inv = 1.0f / L;
        f32x2 o = { 0.0f, 0.0f };
        #pragma unroll
        for (int gg = 0; gg < 4; ++gg) {
            f32x2 v = *(const f32x2*)&slab[(size_t)((gg * 2 + qws) * 32 + ql) * SLAB_ST + lane * 2];
            o[0] += f[gg] * v[0];
            o[1] += f[gg] * v[1];
        }
        o[0] *= inv; o[1] *= inv;
        *(f32x2*)&Out[((size_t)b * L_DIM + q0 + row) * D_DIM + lane * 2] = o;
    }
}

extern "C" void kernel_launch(void* const* d_in, const int* in_sizes, int n_in,
                              void* d_out, int out_size, void* d_ws, size_t ws_size,
                              hipStream_t stream) {
    const float* Q = (const float*)d_in[0];
    const float* V = (const float*)d_in[1];
    float* Out     = (float*)d_out;
    f16* ws        = (f16*)d_ws;   // needs 8 MiB
    prep_v<<<dim3(B_DIM * (L_DIM / KVB)), dim3(256), 0, stream>>>(V, ws);
    attn_fwd<<<dim3(B_DIM * (L_DIM / 64)), dim3(512), 0, stream>>>(Q, ws, Out);
}